// Round 1
// baseline (162.558 us; speedup 1.0000x reference)
//
#include <hip/hip_runtime.h>

#define BB 2
#define SS 2048
#define DD 1024
#define HH 16
#define HDIM 64
#define MTOT 4096  // B*S

typedef unsigned short u16;
typedef __bf16 bf16_t;
typedef bf16_t bf16x8 __attribute__((ext_vector_type(8)));
typedef float floatx4 __attribute__((ext_vector_type(4)));

__device__ __forceinline__ float bf2f(u16 u) {
  union { unsigned int i; float f; } x;
  x.i = ((unsigned int)u) << 16;
  return x.f;
}
// round-to-nearest-even f32 -> bf16 (finite inputs only)
__device__ __forceinline__ u16 f2bf(float f) {
  union { float f; unsigned int i; } x;
  x.f = f;
  unsigned int r = x.i + 0x7fffu + ((x.i >> 16) & 1u);
  return (u16)(r >> 16);
}

// ---------------- kernel 1: fp32 -> bf16 cast of hs, Wq, Wk, Wv ----------------
// float4-granular; segments: hs 1048576 f4, then 3x 262144 f4 for the weights.
__global__ __launch_bounds__(256) void cast_to_bf16(
    const float* __restrict__ hs, const float* __restrict__ wq,
    const float* __restrict__ wk, const float* __restrict__ wv,
    u16* __restrict__ hs_b, u16* __restrict__ wq_b,
    u16* __restrict__ wk_b, u16* __restrict__ wv_b) {
  int fid = blockIdx.x * 256 + threadIdx.x;  // 0 .. 1835007
  const float* src;
  u16* dst;
  int local;
  if (fid < 1048576) { src = hs; dst = hs_b; local = fid; }
  else if (fid < 1310720) { src = wq; dst = wq_b; local = fid - 1048576; }
  else if (fid < 1572864) { src = wk; dst = wk_b; local = fid - 1310720; }
  else { src = wv; dst = wv_b; local = fid - 1572864; }
  float4 v = reinterpret_cast<const float4*>(src)[local];
  ushort4 o;
  o.x = f2bf(v.x); o.y = f2bf(v.y); o.z = f2bf(v.z); o.w = f2bf(v.w);
  reinterpret_cast<ushort4*>(dst)[local] = o;
}

// ---------------- kernel 2: fused QKV projection (gemm_bt) ----------------
// C[m,n] = sum_k A[m,k] * W[n,k] + bias[n].  A: [4096,1024] bf16 row-major,
// W: [1024,1024] bf16 row-major (torch Linear weight). 128x128 tile, BK=32.
// blockIdx.x: 0..23 -> (seg = x>>3 chooses Q/K/V, nt = x&7), blockIdx.y: m-tile.
#define BKK 32
#define LDT 40  // 32 + 8 pad (keeps 16B alignment, breaks bank aliasing)
__global__ __launch_bounds__(256) void qkv_gemm_kernel(
    const u16* __restrict__ A,
    const u16* __restrict__ Wq, const u16* __restrict__ Wk, const u16* __restrict__ Wv,
    const float* __restrict__ bq, const float* __restrict__ bk, const float* __restrict__ bv,
    u16* __restrict__ Qo, u16* __restrict__ Ko, u16* __restrict__ Vo) {
  __shared__ u16 sA[128 * LDT];
  __shared__ u16 sB[128 * LDT];
  const int mt = blockIdx.y, ntall = blockIdx.x;
  const int seg = ntall >> 3, nt = ntall & 7;
  const u16* Wp = (seg == 0) ? Wq : (seg == 1) ? Wk : Wv;
  const float* bp = (seg == 0) ? bq : (seg == 1) ? bk : bv;
  u16* Out = (seg == 0) ? Qo : (seg == 1) ? Ko : Vo;
  const int m0 = mt * 128, n0 = nt * 128;
  const int tid = threadIdx.x;
  const int lane = tid & 63, wave = tid >> 6;
  const int wm = (wave >> 1) * 64, wn = (wave & 1) * 64;
  const int quad = lane >> 4, l16 = lane & 15;
  floatx4 acc[4][4] = {};
  for (int k0 = 0; k0 < DD; k0 += BKK) {
#pragma unroll
    for (int c = 0; c < 2; ++c) {
      int L = tid + c * 256;        // 0..511
      int row = L >> 2;             // 0..127
      int col = (L & 3) * 8;        // 0,8,16,24
      *reinterpret_cast<uint4*>(sA + row * LDT + col) =
          *reinterpret_cast<const uint4*>(A + (size_t)(m0 + row) * DD + k0 + col);
      *reinterpret_cast<uint4*>(sB + row * LDT + col) =
          *reinterpret_cast<const uint4*>(Wp + (size_t)(n0 + row) * DD + k0 + col);
    }
    __syncthreads();
    bf16x8 af[4], bfr[4];
#pragma unroll
    for (int i = 0; i < 4; ++i) {
      af[i]  = *reinterpret_cast<const bf16x8*>(sA + (wm + i * 16 + l16) * LDT + quad * 8);
      bfr[i] = *reinterpret_cast<const bf16x8*>(sB + (wn + i * 16 + l16) * LDT + quad * 8);
    }
#pragma unroll
    for (int i = 0; i < 4; ++i)
#pragma unroll
      for (int j = 0; j < 4; ++j)
        acc[i][j] = __builtin_amdgcn_mfma_f32_16x16x32_bf16(af[i], bfr[j], acc[i][j], 0, 0, 0);
    __syncthreads();
  }
  // epilogue: C/D layout col=lane&15, row=quad*4+r
#pragma unroll
  for (int j = 0; j < 4; ++j) {
    int col = n0 + wn + j * 16 + l16;
    float bias = bp[col];
#pragma unroll
    for (int i = 0; i < 4; ++i) {
#pragma unroll
      for (int r = 0; r < 4; ++r) {
        int row = m0 + wm + i * 16 + quad * 4 + r;
        Out[(size_t)row * DD + col] = f2bf(acc[i][j][r] + bias);
      }
    }
  }
}

// ---------------- kernel 3: partial M[b,h,e,d] = sum_s mask[s]*K[s,e]*V[s,d] ----------------
// grid (32 s-chunks of 64, 32 bh); block 256, each thread a 4x4 (e,d) tile.
__global__ __launch_bounds__(256) void m_partial_kernel(
    const u16* __restrict__ Kb, const u16* __restrict__ Vb,
    const float* __restrict__ am, float* __restrict__ Mpart) {
  __shared__ float sK[64 * 68];
  __shared__ float sV[64 * 68];
  const int chunk = blockIdx.x;  // 0..31
  const int bh = blockIdx.y;     // 0..31
  const int b = bh >> 4, h = bh & 15;
  const int s0 = chunk * 64;
  const int tid = threadIdx.x;
#pragma unroll
  for (int c = 0; c < 2; ++c) {
    int L = tid + c * 256;
    int srow = L >> 3;            // 0..63
    int col = (L & 7) * 8;        // 0..56
    size_t g = (size_t)(b * SS + s0 + srow) * DD + h * HDIM + col;
    uint4 kraw = *reinterpret_cast<const uint4*>(Kb + g);
    uint4 vraw = *reinterpret_cast<const uint4*>(Vb + g);
    float m = (am[b * SS + s0 + srow] >= 0.f) ? 1.f : 0.f;
    unsigned int kw[4] = {kraw.x, kraw.y, kraw.z, kraw.w};
    unsigned int vw[4] = {vraw.x, vraw.y, vraw.z, vraw.w};
#pragma unroll
    for (int q = 0; q < 4; ++q) {
      sK[srow * 68 + col + 2 * q]     = m * bf2f((u16)(kw[q] & 0xffffu));
      sK[srow * 68 + col + 2 * q + 1] = m * bf2f((u16)(kw[q] >> 16));
      sV[srow * 68 + col + 2 * q]     = bf2f((u16)(vw[q] & 0xffffu));
      sV[srow * 68 + col + 2 * q + 1] = bf2f((u16)(vw[q] >> 16));
    }
  }
  __syncthreads();
  const int e0 = (tid & 15) * 4, d0 = (tid >> 4) * 4;
  float acc[4][4] = {};
  for (int s = 0; s < 64; ++s) {
    float4 kk = *reinterpret_cast<const float4*>(&sK[s * 68 + e0]);
    float4 vv = *reinterpret_cast<const float4*>(&sV[s * 68 + d0]);
    float ka[4] = {kk.x, kk.y, kk.z, kk.w};
    float va[4] = {vv.x, vv.y, vv.z, vv.w};
#pragma unroll
    for (int i = 0; i < 4; ++i)
#pragma unroll
      for (int j = 0; j < 4; ++j) acc[i][j] += ka[i] * va[j];
  }
  float* outp = Mpart + ((size_t)(chunk * 32 + bh)) * 4096;
#pragma unroll
  for (int i = 0; i < 4; ++i) {
    float4 o = {acc[i][0], acc[i][1], acc[i][2], acc[i][3]};
    *reinterpret_cast<float4*>(&outp[(e0 + i) * 64 + d0]) = o;
  }
}

// ---------------- kernel 4: reduce 32 partials -> M ----------------
__global__ __launch_bounds__(256) void m_reduce_kernel(
    const float* __restrict__ Mpart, float* __restrict__ M) {
  int idx = blockIdx.x * 256 + threadIdx.x;  // 0..131071
  int bh = idx >> 12, ed = idx & 4095;
  float s = 0.f;
#pragma unroll
  for (int c = 0; c < 32; ++c) s += Mpart[((size_t)(c * 32 + bh) << 12) + ed];
  M[idx] = s;
}

// ---------------- kernel 5: ctx[m, h*64+d] = sum_e Q[m, h*64+e] * M[bh,e,d] ----------------
// grid (64 m-chunks of 64, 16 heads); block 256, each thread a 4x4 (m,d) tile.
__global__ __launch_bounds__(256) void ctx_kernel(
    const u16* __restrict__ Qb, const float* __restrict__ M, float* __restrict__ Out) {
  __shared__ float sM[64 * 68];
  __shared__ float sQ[64 * 68];
  const int mchunk = blockIdx.x;  // 0..63
  const int h = blockIdx.y;       // 0..15
  const int m0 = mchunk * 64;
  const int b = m0 >> 11;         // m0 / 2048
  const int bh = b * HH + h;
  const int tid = threadIdx.x;
  const float* Mp = M + (size_t)bh * 4096;
#pragma unroll
  for (int c = 0; c < 16; ++c) {
    int L = c * 256 + tid;
    int e = L >> 6, d = L & 63;
    sM[e * 68 + d] = Mp[L];
  }
#pragma unroll
  for (int c = 0; c < 2; ++c) {
    int L = tid + c * 256;
    int row = L >> 3, col = (L & 7) * 8;
    uint4 q = *reinterpret_cast<const uint4*>(Qb + (size_t)(m0 + row) * DD + h * HDIM + col);
    unsigned int w[4] = {q.x, q.y, q.z, q.w};
#pragma unroll
    for (int t = 0; t < 4; ++t) {
      sQ[row * 68 + col + 2 * t]     = bf2f((u16)(w[t] & 0xffffu));
      sQ[row * 68 + col + 2 * t + 1] = bf2f((u16)(w[t] >> 16));
    }
  }
  __syncthreads();
  const int d0 = (tid & 15) * 4, ml0 = (tid >> 4) * 4;
  float acc[4][4] = {};
  for (int e = 0; e < 64; ++e) {
    float4 mm = *reinterpret_cast<const float4*>(&sM[e * 68 + d0]);
    float ma[4] = {mm.x, mm.y, mm.z, mm.w};
#pragma unroll
    for (int i = 0; i < 4; ++i) {
      float qv = sQ[(ml0 + i) * 68 + e];
#pragma unroll
      for (int j = 0; j < 4; ++j) acc[i][j] += qv * ma[j];
    }
  }
#pragma unroll
  for (int i = 0; i < 4; ++i) {
    float4 o = {acc[i][0], acc[i][1], acc[i][2], acc[i][3]};
    *reinterpret_cast<float4*>(Out + (size_t)(m0 + ml0 + i) * DD + h * HDIM + d0) = o;
  }
}

extern "C" void kernel_launch(void* const* d_in, const int* in_sizes, int n_in,
                              void* d_out, int out_size, void* d_ws, size_t ws_size,
                              hipStream_t stream) {
  const float* hs = (const float*)d_in[0];
  const float* am = (const float*)d_in[1];
  const float* wq = (const float*)d_in[2];
  const float* bq = (const float*)d_in[3];
  const float* wk = (const float*)d_in[4];
  const float* bk = (const float*)d_in[5];
  const float* wv = (const float*)d_in[6];
  const float* bv = (const float*)d_in[7];
  float* out = (float*)d_out;
  char* ws = (char*)d_ws;

  // workspace layout (bytes), all 16B-aligned; total ~57.2 MB
  u16* hs_b = (u16*)(ws);                  // 8 MiB  [4096,1024] bf16
  u16* wq_b = (u16*)(ws + 8388608);        // 2 MiB
  u16* wk_b = (u16*)(ws + 10485760);       // 2 MiB
  u16* wv_b = (u16*)(ws + 12582912);       // 2 MiB
  u16* q_b  = (u16*)(ws + 14680064);       // 8 MiB
  u16* k_b  = (u16*)(ws + 23068672);       // 8 MiB
  u16* v_b  = (u16*)(ws + 31457280);       // 8 MiB
  float* mpart = (float*)(ws + 39845888);  // 16 MiB [32 chunks][32 bh][64][64] f32
  float* mfull = (float*)(ws + 56623104);  // 512 KiB [32 bh][64][64] f32

  cast_to_bf16<<<7168, 256, 0, stream>>>(hs, wq, wk, wv, hs_b, wq_b, wk_b, wv_b);
  qkv_gemm_kernel<<<dim3(24, 32), 256, 0, stream>>>(hs_b, wq_b, wk_b, wv_b,
                                                    bq, bk, bv, q_b, k_b, v_b);
  m_partial_kernel<<<dim3(32, 32), 256, 0, stream>>>(k_b, v_b, am, mpart);
  m_reduce_kernel<<<512, 256, 0, stream>>>(mpart, mfull);
  ctx_kernel<<<dim3(64, 16), 256, 0, stream>>>(q_b, mfull, out);
}